// Round 1
// baseline (1099.993 us; speedup 1.0000x reference)
//
#include <hip/hip_runtime.h>
#include <hip/hip_bf16.h>
#include <math.h>

// ---------------------------------------------------------------------------
// Problem constants (from reference)
// ---------------------------------------------------------------------------
#define N_NODES 50000
#define N_EDGES 800000
#define NFEAT   512
#define NHID    256
#define NCLASS  128
#define N_UV    2048

// ---------------------------------------------------------------------------
// Tiled fp32 GEMM: C[M,N] = A[M,K] @ B[K,N]  (row-major everywhere)
// 128x128 tile, BK=16, 256 threads, 8x8 per thread in 4+4 split layout.
// Requires: N % 128 == 0, K % 16 == 0. M arbitrary (guarded).
// Optional sigmoid epilogue.
// ---------------------------------------------------------------------------
template <bool SIGMOID>
__global__ __launch_bounds__(256) void gemm_rrr(
    const float* __restrict__ A, const float* __restrict__ B,
    float* __restrict__ C, int M, int N, int K) {
  __shared__ float As[16][132];   // transposed A tile, +4 pad (16B-aligned rows)
  __shared__ float Bs[16][132];

  const int tid = threadIdx.x;
  const int tx = tid & 15;        // N direction
  const int ty = tid >> 4;        // M direction
  const int m0 = blockIdx.y * 128;
  const int n0 = blockIdx.x * 128;

  // A-load mapping: 64 rows x 16 cols per pass (2 passes)
  const int arow  = tid >> 2;         // 0..63
  const int acol4 = (tid & 3) * 4;    // 0,4,8,12
  // B-load mapping: 8 rows x 128 cols per pass (2 passes)
  const int brow  = tid >> 5;         // 0..7
  const int bcol4 = (tid & 31) * 4;   // 0..124

  float acc[8][8];
#pragma unroll
  for (int i = 0; i < 8; ++i)
#pragma unroll
    for (int j = 0; j < 8; ++j) acc[i][j] = 0.f;

  for (int k0 = 0; k0 < K; k0 += 16) {
    // ---- stage A tile (transposed into LDS) ----
#pragma unroll
    for (int p = 0; p < 2; ++p) {
      const int mt = p * 64 + arow;
      const int m  = m0 + mt;
      float4 av = make_float4(0.f, 0.f, 0.f, 0.f);
      if (m < M) av = *(const float4*)&A[(size_t)m * K + k0 + acol4];
      As[acol4 + 0][mt] = av.x;
      As[acol4 + 1][mt] = av.y;
      As[acol4 + 2][mt] = av.z;
      As[acol4 + 3][mt] = av.w;
    }
    // ---- stage B tile ----
#pragma unroll
    for (int p = 0; p < 2; ++p) {
      const int kt = p * 8 + brow;
      const float4 bv = *(const float4*)&B[(size_t)(k0 + kt) * N + n0 + bcol4];
      *(float4*)&Bs[kt][bcol4] = bv;
    }
    __syncthreads();

    // ---- compute ----
#pragma unroll
    for (int k = 0; k < 16; ++k) {
      float a[8], b[8];
      *(float4*)&a[0] = *(const float4*)&As[k][ty * 4];
      *(float4*)&a[4] = *(const float4*)&As[k][64 + ty * 4];
      *(float4*)&b[0] = *(const float4*)&Bs[k][tx * 4];
      *(float4*)&b[4] = *(const float4*)&Bs[k][64 + tx * 4];
#pragma unroll
      for (int i = 0; i < 8; ++i)
#pragma unroll
        for (int j = 0; j < 8; ++j)
          acc[i][j] = fmaf(a[i], b[j], acc[i][j]);
    }
    __syncthreads();
  }

  // ---- store ----
#pragma unroll
  for (int ih = 0; ih < 2; ++ih) {
#pragma unroll
    for (int i = 0; i < 4; ++i) {
      const int m = m0 + ih * 64 + ty * 4 + i;
      if (m < M) {
#pragma unroll
        for (int jh = 0; jh < 2; ++jh) {
          float4 v = *(float4*)&acc[ih * 4 + i][jh * 4];
          if (SIGMOID) {
            v.x = 1.f / (1.f + expf(-v.x));
            v.y = 1.f / (1.f + expf(-v.y));
            v.z = 1.f / (1.f + expf(-v.z));
            v.w = 1.f / (1.f + expf(-v.w));
          }
          *(float4*)&C[(size_t)m * N + n0 + jh * 64 + tx * 4] = v;
        }
      }
    }
  }
}

// ---------------------------------------------------------------------------
// SpMM via sorted-COO (CSR-like): one block per node, F threads (one/feature).
// out[node][f] = sum_{e: row[e]==node} val[e] * S[col[e]][f]  + bias[f]
// adj_row is sorted -> binary search the edge range for this node.
// ---------------------------------------------------------------------------
template <int F, bool RELU>
__global__ __launch_bounds__(F) void spmm_sorted(
    const float* __restrict__ S, const int* __restrict__ rows,
    const int* __restrict__ cols, const float* __restrict__ vals,
    const float* __restrict__ bias, float* __restrict__ out) {
  const int node = blockIdx.x;
  const int tid = threadIdx.x;

  __shared__ int s_lo, s_hi;
  if (tid == 0) {
    int lo = 0, hi = N_EDGES;                       // lower_bound(node)
    while (lo < hi) { int mid = (lo + hi) >> 1; if (rows[mid] < node) lo = mid + 1; else hi = mid; }
    s_lo = lo;
    int lo2 = lo, hi2 = N_EDGES;                    // upper_bound(node)
    while (lo2 < hi2) { int mid = (lo2 + hi2) >> 1; if (rows[mid] <= node) lo2 = mid + 1; else hi2 = mid; }
    s_hi = lo2;
  }
  __syncthreads();

  float acc = 0.f;
  const int lo = s_lo, hi = s_hi;
  for (int e = lo; e < hi; ++e) {
    const int c = cols[e];
    const float w = vals[e];
    acc = fmaf(w, S[(size_t)c * F + tid], acc);
  }
  acc += bias[tid];
  if (RELU) acc = fmaxf(acc, 0.f);
  out[(size_t)node * F + tid] = acc;
}

// ---------------------------------------------------------------------------
// Small helpers for the edge-scoring head
// ---------------------------------------------------------------------------
__global__ __launch_bounds__(128) void transpose_we(
    const float* __restrict__ We, float* __restrict__ WeT) {
  const int k = blockIdx.x;      // 128 blocks
  const int c = threadIdx.x;     // 128 threads
  WeT[k * NCLASS + c] = We[c * NCLASS + k];
}

// zug[i][k] = Z[u[i]][k]
__global__ __launch_bounds__(128) void gather_rows(
    const float* __restrict__ Z, const int* __restrict__ idx,
    float* __restrict__ out) {
  const int i = blockIdx.x;
  const int k = threadIdx.x;
  out[i * NCLASS + k] = Z[(size_t)idx[i] * NCLASS + k];
}

// zvT[k][j] = Z[v[j]][k]   (transposed gather so scoring is a plain RRR GEMM)
__global__ __launch_bounds__(256) void gather_rows_t(
    const float* __restrict__ Z, const int* __restrict__ idx,
    float* __restrict__ out) {
  const int g = blockIdx.x * 256 + threadIdx.x;   // 2048*128 total
  const int j = g & (N_UV - 1);
  const int k = g >> 11;
  out[(size_t)k * N_UV + j] = Z[(size_t)idx[j] * NCLASS + k];
}

// ---------------------------------------------------------------------------
// Launch
// ---------------------------------------------------------------------------
extern "C" void kernel_launch(void* const* d_in, const int* in_sizes, int n_in,
                              void* d_out, int out_size, void* d_ws, size_t ws_size,
                              hipStream_t stream) {
  const int*   u       = (const int*)  d_in[0];
  const int*   v       = (const int*)  d_in[1];
  const float* x       = (const float*)d_in[2];
  const int*   adj_row = (const int*)  d_in[3];
  const int*   adj_col = (const int*)  d_in[4];
  const float* adj_val = (const float*)d_in[5];
  const float* W1      = (const float*)d_in[6];
  const float* b1      = (const float*)d_in[7];
  const float* W2      = (const float*)d_in[8];
  const float* b2      = (const float*)d_in[9];
  const float* We      = (const float*)d_in[10];
  float* out = (float*)d_out;

  float* ws = (float*)d_ws;
  // Region R1: [0, 12.8M) floats ; Region R2: [12.8M, 25.6M+..)
  float* S1  = ws;                                   // 50000*256
  float* H   = ws + (size_t)N_NODES * NHID;          // 50000*256
  float* S2  = ws;                                   // 50000*128 (S1 dead)
  float* Z   = ws + (size_t)N_NODES * NCLASS;        // 50000*128 (still in R1)
  float* WeT = H;                                    // 128*128   (H dead after GEMM2)
  float* ZUG = WeT + NCLASS * NCLASS;                // 2048*128
  float* ZVT = ZUG + N_UV * NCLASS;                  // 128*2048
  float* ZU  = ZVT + N_UV * NCLASS;                  // 2048*128

  // 1) S1 = x @ W1            [50000,512]x[512,256]
  gemm_rrr<false><<<dim3(NHID / 128, (N_NODES + 127) / 128), 256, 0, stream>>>(
      x, W1, S1, N_NODES, NHID, NFEAT);

  // 2) H = relu(A @ S1 + b1)
  spmm_sorted<NHID, true><<<N_NODES, NHID, 0, stream>>>(
      S1, adj_row, adj_col, adj_val, b1, H);

  // 3) S2 = H @ W2            [50000,256]x[256,128]
  gemm_rrr<false><<<dim3(NCLASS / 128, (N_NODES + 127) / 128), 256, 0, stream>>>(
      H, W2, S2, N_NODES, NCLASS, NHID);

  // 4) Z = A @ S2 + b2
  spmm_sorted<NCLASS, false><<<N_NODES, NCLASS, 0, stream>>>(
      S2, adj_row, adj_col, adj_val, b2, Z);

  // 5) head: WeT, gathers
  transpose_we<<<NCLASS, NCLASS, 0, stream>>>(We, WeT);
  gather_rows<<<N_UV, NCLASS, 0, stream>>>(Z, u, ZUG);
  gather_rows_t<<<(N_UV * NCLASS) / 256, 256, 0, stream>>>(Z, v, ZVT);

  // 6) ZU = ZUG @ WeT         [2048,128]x[128,128]
  gemm_rrr<false><<<dim3(NCLASS / 128, N_UV / 128), 256, 0, stream>>>(
      ZUG, WeT, ZU, N_UV, NCLASS, NCLASS);

  // 7) out = sigmoid(ZU @ ZVT) [2048,128]x[128,2048]
  gemm_rrr<true><<<dim3(N_UV / 128, N_UV / 128), 256, 0, stream>>>(
      ZU, ZVT, out, N_UV, N_UV, NCLASS);
}

// Round 2
// 806.619 us; speedup vs baseline: 1.3637x; 1.3637x over previous
//
#include <hip/hip_runtime.h>
#include <hip/hip_bf16.h>
#include <math.h>

// ---------------------------------------------------------------------------
// Problem constants (from reference)
// ---------------------------------------------------------------------------
#define N_NODES 50000
#define N_EDGES 800000
#define NFEAT   512
#define NHID    256
#define NCLASS  128
#define N_UV    2048

typedef __bf16 bf16x8 __attribute__((ext_vector_type(8)));
typedef short  s16x8  __attribute__((ext_vector_type(8)));
typedef float  f32x4  __attribute__((ext_vector_type(4)));

__device__ __forceinline__ unsigned short bf16_rn(float f) {
  unsigned u = __float_as_uint(f);
  u += 0x7fffu + ((u >> 16) & 1u);
  return (unsigned short)(u >> 16);
}
__device__ __forceinline__ float bf16_to_f(unsigned short h) {
  return __uint_as_float(((unsigned)h) << 16);
}

// ---------------------------------------------------------------------------
// Split-bf16 MFMA GEMM: C[M,N] = A[M,K] @ BT[N,K]^T  (fp32-quality via
// Ahi*Bhi + Ahi*Blo + Alo*Bhi). 128x128 tile, BK=32, 256 thr, 4 waves 2x2,
// each wave 4x4 tiles of mfma_f32_16x16x32_bf16.
// ASPLIT=true: A is fp32, split during staging. else: Ahi/Alo bf16 arrays.
// Requires N%128==0, K%32==0; M guarded.
// ---------------------------------------------------------------------------
#define LDSPAD 40   // 32 + 8 shorts: keeps 16B alignment, breaks pow2 stride

template <bool ASPLIT>
__global__ __launch_bounds__(256, 2) void gemm_mfma_split(
    const float* __restrict__ Af,
    const unsigned short* __restrict__ Ahi, const unsigned short* __restrict__ Alo,
    const unsigned short* __restrict__ BThi, const unsigned short* __restrict__ BTlo,
    float* __restrict__ C, int M, int N, int K) {
  __shared__ unsigned short sAh[128 * LDSPAD];
  __shared__ unsigned short sAl[128 * LDSPAD];
  __shared__ unsigned short sBh[128 * LDSPAD];
  __shared__ unsigned short sBl[128 * LDSPAD];

  const int tid  = threadIdx.x;
  const int lane = tid & 63;
  const int wave = tid >> 6;
  const int wm   = (wave >> 1) << 6;   // wave row offset in 128-tile
  const int wn   = (wave & 1) << 6;    // wave col offset
  const int lm   = lane & 15;
  const int quad = lane >> 4;
  const int m0   = blockIdx.y * 128;
  const int n0   = blockIdx.x * 128;

  f32x4 acc[4][4];
#pragma unroll
  for (int i = 0; i < 4; ++i)
#pragma unroll
    for (int j = 0; j < 4; ++j)
#pragma unroll
      for (int r = 0; r < 4; ++r) acc[i][j][r] = 0.f;

  for (int k0 = 0; k0 < K; k0 += 32) {
    // ---- stage A (hi/lo) ----
    if (ASPLIT) {
#pragma unroll
      for (int p = 0; p < 4; ++p) {
        const int row = p * 32 + (tid >> 3);
        const int col = (tid & 7) * 4;
        const int m = m0 + row;
        float4 v = make_float4(0.f, 0.f, 0.f, 0.f);
        if (m < M) v = *(const float4*)&Af[(size_t)m * K + k0 + col];
        ushort4 hv, lv;
        hv.x = bf16_rn(v.x); lv.x = bf16_rn(v.x - bf16_to_f(hv.x));
        hv.y = bf16_rn(v.y); lv.y = bf16_rn(v.y - bf16_to_f(hv.y));
        hv.z = bf16_rn(v.z); lv.z = bf16_rn(v.z - bf16_to_f(hv.z));
        hv.w = bf16_rn(v.w); lv.w = bf16_rn(v.w - bf16_to_f(hv.w));
        *(ushort4*)&sAh[row * LDSPAD + col] = hv;
        *(ushort4*)&sAl[row * LDSPAD + col] = lv;
      }
    } else {
#pragma unroll
      for (int p = 0; p < 2; ++p) {
        const int row = p * 64 + (tid >> 2);
        const int col = (tid & 3) * 8;
        const int m = m0 + row;
        s16x8 h, l;
#pragma unroll
        for (int e = 0; e < 8; ++e) { h[e] = 0; l[e] = 0; }
        if (m < M) {
          h = *(const s16x8*)&Ahi[(size_t)m * K + k0 + col];
          l = *(const s16x8*)&Alo[(size_t)m * K + k0 + col];
        }
        *(s16x8*)&sAh[row * LDSPAD + col] = h;
        *(s16x8*)&sAl[row * LDSPAD + col] = l;
      }
    }
    // ---- stage B (hi/lo), N%128==0 so no guard ----
#pragma unroll
    for (int p = 0; p < 2; ++p) {
      const int row = p * 64 + (tid >> 2);
      const int col = (tid & 3) * 8;
      *(s16x8*)&sBh[row * LDSPAD + col] = *(const s16x8*)&BThi[(size_t)(n0 + row) * K + k0 + col];
      *(s16x8*)&sBl[row * LDSPAD + col] = *(const s16x8*)&BTlo[(size_t)(n0 + row) * K + k0 + col];
    }
    __syncthreads();

    // ---- fragments + MFMA ----
    bf16x8 aH[4], aL[4], bH[4], bL[4];
#pragma unroll
    for (int i = 0; i < 4; ++i) {
      const int r = wm + i * 16 + lm;
      aH[i] = __builtin_bit_cast(bf16x8, *(const s16x8*)&sAh[r * LDSPAD + quad * 8]);
      aL[i] = __builtin_bit_cast(bf16x8, *(const s16x8*)&sAl[r * LDSPAD + quad * 8]);
    }
#pragma unroll
    for (int j = 0; j < 4; ++j) {
      const int r = wn + j * 16 + lm;
      bH[j] = __builtin_bit_cast(bf16x8, *(const s16x8*)&sBh[r * LDSPAD + quad * 8]);
      bL[j] = __builtin_bit_cast(bf16x8, *(const s16x8*)&sBl[r * LDSPAD + quad * 8]);
    }
#pragma unroll
    for (int i = 0; i < 4; ++i)
#pragma unroll
      for (int j = 0; j < 4; ++j) {
        acc[i][j] = __builtin_amdgcn_mfma_f32_16x16x32_bf16(aH[i], bH[j], acc[i][j], 0, 0, 0);
        acc[i][j] = __builtin_amdgcn_mfma_f32_16x16x32_bf16(aH[i], bL[j], acc[i][j], 0, 0, 0);
        acc[i][j] = __builtin_amdgcn_mfma_f32_16x16x32_bf16(aL[i], bH[j], acc[i][j], 0, 0, 0);
      }
    __syncthreads();
  }

  // ---- epilogue: C/D layout col=lane&15, row=quad*4+reg ----
#pragma unroll
  for (int i = 0; i < 4; ++i)
#pragma unroll
    for (int j = 0; j < 4; ++j) {
      const int col = n0 + wn + j * 16 + lm;
#pragma unroll
      for (int r = 0; r < 4; ++r) {
        const int row = m0 + wm + i * 16 + quad * 4 + r;
        if (row < M) C[(size_t)row * N + col] = acc[i][j][r];
      }
    }
}

// ---------------------------------------------------------------------------
// Weight prep: T[n*K+k] = split(W[k*N+n])  (transpose + bf16 hi/lo split)
// ---------------------------------------------------------------------------
__global__ __launch_bounds__(256) void split_transpose(
    const float* __restrict__ W, unsigned short* __restrict__ Thi,
    unsigned short* __restrict__ Tlo, int K, int N) {
  const int idx = blockIdx.x * 256 + threadIdx.x;
  if (idx >= K * N) return;
  const int n = idx / K;
  const int k = idx - n * K;
  const float f = W[(size_t)k * N + n];
  const unsigned short h = bf16_rn(f);
  Thi[idx] = h;
  Tlo[idx] = bf16_rn(f - bf16_to_f(h));
}

// ---------------------------------------------------------------------------
// SpMM via sorted-COO: one block/node, F threads. Optional fused relu and
// bf16 hi/lo split output (for feeding the next MFMA GEMM).
// ---------------------------------------------------------------------------
template <int F, bool RELU, bool SPLIT>
__global__ __launch_bounds__(F) void spmm_sorted(
    const float* __restrict__ S, const int* __restrict__ rows,
    const int* __restrict__ cols, const float* __restrict__ vals,
    const float* __restrict__ bias, float* __restrict__ outF,
    unsigned short* __restrict__ outHi, unsigned short* __restrict__ outLo) {
  const int node = blockIdx.x;
  const int tid = threadIdx.x;

  __shared__ int s_lo, s_hi;
  if (tid == 0) {
    int lo = 0, hi = N_EDGES;
    while (lo < hi) { int mid = (lo + hi) >> 1; if (rows[mid] < node) lo = mid + 1; else hi = mid; }
    s_lo = lo;
    int lo2 = lo, hi2 = N_EDGES;
    while (lo2 < hi2) { int mid = (lo2 + hi2) >> 1; if (rows[mid] <= node) lo2 = mid + 1; else hi2 = mid; }
    s_hi = lo2;
  }
  __syncthreads();

  float acc = 0.f;
  const int lo = s_lo, hi = s_hi;
  for (int e = lo; e < hi; ++e) {
    const int c = cols[e];
    const float w = vals[e];
    acc = fmaf(w, S[(size_t)c * F + tid], acc);
  }
  acc += bias[tid];
  if (RELU) acc = fmaxf(acc, 0.f);
  const size_t o = (size_t)node * F + tid;
  if (SPLIT) {
    const unsigned short h = bf16_rn(acc);
    outHi[o] = h;
    outLo[o] = bf16_rn(acc - bf16_to_f(h));
  } else {
    outF[o] = acc;
  }
}

// ---------------------------------------------------------------------------
// fp32 tiled GEMM (head only): C[M,N]=A[M,K]@B[K,N], 128x128, optional sigmoid
// ---------------------------------------------------------------------------
template <bool SIGMOID>
__global__ __launch_bounds__(256) void gemm_rrr(
    const float* __restrict__ A, const float* __restrict__ B,
    float* __restrict__ C, int M, int N, int K) {
  __shared__ float As[16][132];
  __shared__ float Bs[16][132];

  const int tid = threadIdx.x;
  const int tx = tid & 15;
  const int ty = tid >> 4;
  const int m0 = blockIdx.y * 128;
  const int n0 = blockIdx.x * 128;

  const int arow  = tid >> 2;
  const int acol4 = (tid & 3) * 4;
  const int brow  = tid >> 5;
  const int bcol4 = (tid & 31) * 4;

  float acc[8][8];
#pragma unroll
  for (int i = 0; i < 8; ++i)
#pragma unroll
    for (int j = 0; j < 8; ++j) acc[i][j] = 0.f;

  for (int k0 = 0; k0 < K; k0 += 16) {
#pragma unroll
    for (int p = 0; p < 2; ++p) {
      const int mt = p * 64 + arow;
      const int m  = m0 + mt;
      float4 av = make_float4(0.f, 0.f, 0.f, 0.f);
      if (m < M) av = *(const float4*)&A[(size_t)m * K + k0 + acol4];
      As[acol4 + 0][mt] = av.x;
      As[acol4 + 1][mt] = av.y;
      As[acol4 + 2][mt] = av.z;
      As[acol4 + 3][mt] = av.w;
    }
#pragma unroll
    for (int p = 0; p < 2; ++p) {
      const int kt = p * 8 + brow;
      *(float4*)&Bs[kt][bcol4] = *(const float4*)&B[(size_t)(k0 + kt) * N + n0 + bcol4];
    }
    __syncthreads();
#pragma unroll
    for (int k = 0; k < 16; ++k) {
      float a[8], b[8];
      *(float4*)&a[0] = *(const float4*)&As[k][ty * 4];
      *(float4*)&a[4] = *(const float4*)&As[k][64 + ty * 4];
      *(float4*)&b[0] = *(const float4*)&Bs[k][tx * 4];
      *(float4*)&b[4] = *(const float4*)&Bs[k][64 + tx * 4];
#pragma unroll
      for (int i = 0; i < 8; ++i)
#pragma unroll
        for (int j = 0; j < 8; ++j)
          acc[i][j] = fmaf(a[i], b[j], acc[i][j]);
    }
    __syncthreads();
  }

#pragma unroll
  for (int ih = 0; ih < 2; ++ih)
#pragma unroll
    for (int i = 0; i < 4; ++i) {
      const int m = m0 + ih * 64 + ty * 4 + i;
      if (m < M) {
#pragma unroll
        for (int jh = 0; jh < 2; ++jh) {
          float4 v = *(float4*)&acc[ih * 4 + i][jh * 4];
          if (SIGMOID) {
            v.x = 1.f / (1.f + expf(-v.x));
            v.y = 1.f / (1.f + expf(-v.y));
            v.z = 1.f / (1.f + expf(-v.z));
            v.w = 1.f / (1.f + expf(-v.w));
          }
          *(float4*)&C[(size_t)m * N + n0 + jh * 64 + tx * 4] = v;
        }
      }
    }
}

// ---------------------------------------------------------------------------
// Head helpers
// ---------------------------------------------------------------------------
__global__ __launch_bounds__(128) void transpose_we(
    const float* __restrict__ We, float* __restrict__ WeT) {
  WeT[blockIdx.x * NCLASS + threadIdx.x] = We[threadIdx.x * NCLASS + blockIdx.x];
}

__global__ __launch_bounds__(128) void gather_rows(
    const float* __restrict__ Z, const int* __restrict__ idx,
    float* __restrict__ out) {
  out[blockIdx.x * NCLASS + threadIdx.x] =
      Z[(size_t)idx[blockIdx.x] * NCLASS + threadIdx.x];
}

__global__ __launch_bounds__(256) void gather_rows_t(
    const float* __restrict__ Z, const int* __restrict__ idx,
    float* __restrict__ out) {
  const int g = blockIdx.x * 256 + threadIdx.x;
  const int j = g & (N_UV - 1);
  const int k = g >> 11;
  out[(size_t)k * N_UV + j] = Z[(size_t)idx[j] * NCLASS + k];
}

// ---------------------------------------------------------------------------
// Launch
// ---------------------------------------------------------------------------
extern "C" void kernel_launch(void* const* d_in, const int* in_sizes, int n_in,
                              void* d_out, int out_size, void* d_ws, size_t ws_size,
                              hipStream_t stream) {
  const int*   u       = (const int*)  d_in[0];
  const int*   v       = (const int*)  d_in[1];
  const float* x       = (const float*)d_in[2];
  const int*   adj_row = (const int*)  d_in[3];
  const int*   adj_col = (const int*)  d_in[4];
  const float* adj_val = (const float*)d_in[5];
  const float* W1      = (const float*)d_in[6];
  const float* b1      = (const float*)d_in[7];
  const float* W2      = (const float*)d_in[8];
  const float* b2      = (const float*)d_in[9];
  const float* We      = (const float*)d_in[10];
  float* out = (float*)d_out;

  char* wsb = (char*)d_ws;
  // Region A [0, 51.2MB): S1; after spmm1 dead -> S2 [0,25.6) + Z [25.6,51.2)
  float* S1 = (float*)wsb;
  float* S2 = (float*)wsb;
  float* Z  = (float*)(wsb + (size_t)N_NODES * NCLASS * sizeof(float));
  // Region B [51.2MB, 102.4MB): Hhi/Hlo; after GEMM2 dead -> head scratch
  char* rB = wsb + (size_t)N_NODES * NHID * sizeof(float);
  unsigned short* Hhi = (unsigned short*)rB;
  unsigned short* Hlo = Hhi + (size_t)N_NODES * NHID;
  float* WeT = (float*)rB;
  float* ZUG = WeT + NCLASS * NCLASS;
  float* ZVT = ZUG + N_UV * NCLASS;
  float* ZU  = ZVT + N_UV * NCLASS;
  // Split weights parked in d_out (dead until the final GEMM rewrites out)
  unsigned short* W1Thi = (unsigned short*)out;
  unsigned short* W1Tlo = W1Thi + NHID * NFEAT;
  unsigned short* W2Thi = W1Tlo + NHID * NFEAT;
  unsigned short* W2Tlo = W2Thi + NCLASS * NHID;

  // 0) weight prep (transpose + hi/lo split)
  split_transpose<<<(NFEAT * NHID + 255) / 256, 256, 0, stream>>>(W1, W1Thi, W1Tlo, NFEAT, NHID);
  split_transpose<<<(NHID * NCLASS + 255) / 256, 256, 0, stream>>>(W2, W2Thi, W2Tlo, NHID, NCLASS);

  // 1) S1 = x @ W1  (MFMA split-bf16, A split on the fly from fp32)
  gemm_mfma_split<true><<<dim3(NHID / 128, (N_NODES + 127) / 128), 256, 0, stream>>>(
      x, nullptr, nullptr, W1Thi, W1Tlo, S1, N_NODES, NHID, NFEAT);

  // 2) Hhi/Hlo = split(relu(A @ S1 + b1))
  spmm_sorted<NHID, true, true><<<N_NODES, NHID, 0, stream>>>(
      S1, adj_row, adj_col, adj_val, b1, nullptr, Hhi, Hlo);

  // 3) S2 = H @ W2  (MFMA split-bf16, A pre-split)
  gemm_mfma_split<false><<<dim3(NCLASS / 128, (N_NODES + 127) / 128), 256, 0, stream>>>(
      nullptr, Hhi, Hlo, W2Thi, W2Tlo, S2, N_NODES, NCLASS, NHID);

  // 4) Z = A @ S2 + b2
  spmm_sorted<NCLASS, false, false><<<N_NODES, NCLASS, 0, stream>>>(
      S2, adj_row, adj_col, adj_val, b2, Z, nullptr, nullptr);

  // 5) head
  transpose_we<<<NCLASS, NCLASS, 0, stream>>>(We, WeT);
  gather_rows<<<N_UV, NCLASS, 0, stream>>>(Z, u, ZUG);
  gather_rows_t<<<(N_UV * NCLASS) / 256, 256, 0, stream>>>(Z, v, ZVT);

  // 6) ZU = ZUG @ WeT
  gemm_rrr<false><<<dim3(NCLASS / 128, N_UV / 128), 256, 0, stream>>>(
      ZUG, WeT, ZU, N_UV, NCLASS, NCLASS);

  // 7) out = sigmoid(ZU @ ZVT)
  gemm_rrr<true><<<dim3(N_UV / 128, N_UV / 128), 256, 0, stream>>>(
      ZU, ZVT, out, N_UV, N_UV, NCLASS);
}

// Round 3
// 513.528 us; speedup vs baseline: 2.1420x; 1.5707x over previous
//
#include <hip/hip_runtime.h>
#include <hip/hip_bf16.h>
#include <math.h>

// ---------------------------------------------------------------------------
// Problem constants (from reference)
// ---------------------------------------------------------------------------
#define N_NODES 50000
#define N_EDGES 800000
#define NFEAT   512
#define NHID    256
#define NCLASS  128
#define N_UV    2048

typedef __bf16 bf16x8 __attribute__((ext_vector_type(8)));
typedef short  s16x8  __attribute__((ext_vector_type(8)));
typedef float  f32x4  __attribute__((ext_vector_type(4)));

__device__ __forceinline__ unsigned short bf16_rn(float f) {
  unsigned u = __float_as_uint(f);
  u += 0x7fffu + ((u >> 16) & 1u);
  return (unsigned short)(u >> 16);
}
__device__ __forceinline__ float bf16_to_f(unsigned short h) {
  return __uint_as_float(((unsigned)h) << 16);
}

// ---------------------------------------------------------------------------
// Split-bf16 MFMA GEMM: C[M,N] = A[M,K] @ BT[N,K]^T  (fp32-quality via
// Ahi*Bhi + Ahi*Blo + Alo*Bhi). 128x128 tile, BK=32, 256 thr, 4 waves 2x2,
// each wave 4x4 tiles of mfma_f32_16x16x32_bf16.
// ---------------------------------------------------------------------------
#define LDSPAD 40   // 32 + 8 shorts: keeps 16B alignment, breaks pow2 stride

template <bool ASPLIT>
__global__ __launch_bounds__(256, 2) void gemm_mfma_split(
    const float* __restrict__ Af,
    const unsigned short* __restrict__ Ahi, const unsigned short* __restrict__ Alo,
    const unsigned short* __restrict__ BThi, const unsigned short* __restrict__ BTlo,
    float* __restrict__ C, int M, int N, int K) {
  __shared__ unsigned short sAh[128 * LDSPAD];
  __shared__ unsigned short sAl[128 * LDSPAD];
  __shared__ unsigned short sBh[128 * LDSPAD];
  __shared__ unsigned short sBl[128 * LDSPAD];

  const int tid  = threadIdx.x;
  const int lane = tid & 63;
  const int wave = tid >> 6;
  const int wm   = (wave >> 1) << 6;
  const int wn   = (wave & 1) << 6;
  const int lm   = lane & 15;
  const int quad = lane >> 4;
  const int m0   = blockIdx.y * 128;
  const int n0   = blockIdx.x * 128;

  f32x4 acc[4][4];
#pragma unroll
  for (int i = 0; i < 4; ++i)
#pragma unroll
    for (int j = 0; j < 4; ++j)
#pragma unroll
      for (int r = 0; r < 4; ++r) acc[i][j][r] = 0.f;

  for (int k0 = 0; k0 < K; k0 += 32) {
    if (ASPLIT) {
#pragma unroll
      for (int p = 0; p < 4; ++p) {
        const int row = p * 32 + (tid >> 3);
        const int col = (tid & 7) * 4;
        const int m = m0 + row;
        float4 v = make_float4(0.f, 0.f, 0.f, 0.f);
        if (m < M) v = *(const float4*)&Af[(size_t)m * K + k0 + col];
        ushort4 hv, lv;
        hv.x = bf16_rn(v.x); lv.x = bf16_rn(v.x - bf16_to_f(hv.x));
        hv.y = bf16_rn(v.y); lv.y = bf16_rn(v.y - bf16_to_f(hv.y));
        hv.z = bf16_rn(v.z); lv.z = bf16_rn(v.z - bf16_to_f(hv.z));
        hv.w = bf16_rn(v.w); lv.w = bf16_rn(v.w - bf16_to_f(hv.w));
        *(ushort4*)&sAh[row * LDSPAD + col] = hv;
        *(ushort4*)&sAl[row * LDSPAD + col] = lv;
      }
    } else {
#pragma unroll
      for (int p = 0; p < 2; ++p) {
        const int row = p * 64 + (tid >> 2);
        const int col = (tid & 3) * 8;
        const int m = m0 + row;
        s16x8 h, l;
#pragma unroll
        for (int e = 0; e < 8; ++e) { h[e] = 0; l[e] = 0; }
        if (m < M) {
          h = *(const s16x8*)&Ahi[(size_t)m * K + k0 + col];
          l = *(const s16x8*)&Alo[(size_t)m * K + k0 + col];
        }
        *(s16x8*)&sAh[row * LDSPAD + col] = h;
        *(s16x8*)&sAl[row * LDSPAD + col] = l;
      }
    }
#pragma unroll
    for (int p = 0; p < 2; ++p) {
      const int row = p * 64 + (tid >> 2);
      const int col = (tid & 3) * 8;
      *(s16x8*)&sBh[row * LDSPAD + col] = *(const s16x8*)&BThi[(size_t)(n0 + row) * K + k0 + col];
      *(s16x8*)&sBl[row * LDSPAD + col] = *(const s16x8*)&BTlo[(size_t)(n0 + row) * K + k0 + col];
    }
    __syncthreads();

    bf16x8 aH[4], aL[4], bH[4], bL[4];
#pragma unroll
    for (int i = 0; i < 4; ++i) {
      const int r = wm + i * 16 + lm;
      aH[i] = __builtin_bit_cast(bf16x8, *(const s16x8*)&sAh[r * LDSPAD + quad * 8]);
      aL[i] = __builtin_bit_cast(bf16x8, *(const s16x8*)&sAl[r * LDSPAD + quad * 8]);
    }
#pragma unroll
    for (int j = 0; j < 4; ++j) {
      const int r = wn + j * 16 + lm;
      bH[j] = __builtin_bit_cast(bf16x8, *(const s16x8*)&sBh[r * LDSPAD + quad * 8]);
      bL[j] = __builtin_bit_cast(bf16x8, *(const s16x8*)&sBl[r * LDSPAD + quad * 8]);
    }
#pragma unroll
    for (int i = 0; i < 4; ++i)
#pragma unroll
      for (int j = 0; j < 4; ++j) {
        acc[i][j] = __builtin_amdgcn_mfma_f32_16x16x32_bf16(aH[i], bH[j], acc[i][j], 0, 0, 0);
        acc[i][j] = __builtin_amdgcn_mfma_f32_16x16x32_bf16(aH[i], bL[j], acc[i][j], 0, 0, 0);
        acc[i][j] = __builtin_amdgcn_mfma_f32_16x16x32_bf16(aL[i], bH[j], acc[i][j], 0, 0, 0);
      }
    __syncthreads();
  }

#pragma unroll
  for (int i = 0; i < 4; ++i)
#pragma unroll
    for (int j = 0; j < 4; ++j) {
      const int col = n0 + wn + j * 16 + lm;
#pragma unroll
      for (int r = 0; r < 4; ++r) {
        const int row = m0 + wm + i * 16 + quad * 4 + r;
        if (row < M) C[(size_t)row * N + col] = acc[i][j][r];
      }
    }
}

// ---------------------------------------------------------------------------
// Weight prep: T[n*K+k] = split(W[k*N+n])
// ---------------------------------------------------------------------------
__global__ __launch_bounds__(256) void split_transpose(
    const float* __restrict__ W, unsigned short* __restrict__ Thi,
    unsigned short* __restrict__ Tlo, int K, int N) {
  const int idx = blockIdx.x * 256 + threadIdx.x;
  if (idx >= K * N) return;
  const int n = idx / K;
  const int k = idx - n * K;
  const float f = W[(size_t)k * N + n];
  const unsigned short h = bf16_rn(f);
  Thi[idx] = h;
  Tlo[idx] = bf16_rn(f - bf16_to_f(h));
}

// ---------------------------------------------------------------------------
// row_ptr[n] = lower_bound(rows, n); rows sorted. Edge-parallel build.
// ---------------------------------------------------------------------------
__global__ __launch_bounds__(256) void build_row_ptr(
    const int* __restrict__ rows, int* __restrict__ row_ptr) {
  const int e = blockIdx.x * 256 + threadIdx.x;
  if (e >= N_EDGES) return;
  const int r = rows[e];
  const int rprev = (e == 0) ? -1 : rows[e - 1];
  for (int n = rprev + 1; n <= r; ++n) row_ptr[n] = e;
  if (e == N_EDGES - 1) {
    for (int n = r + 1; n <= N_NODES; ++n) row_ptr[n] = N_EDGES;
  }
}

// ---------------------------------------------------------------------------
// SpMM F=256: one wave per node, lane covers 4 feats (float4), 4-edge unroll.
// Fused relu + bf16 hi/lo split output.
// ---------------------------------------------------------------------------
__global__ __launch_bounds__(256) void spmm256_split(
    const float4* __restrict__ S4, const int* __restrict__ row_ptr,
    const int* __restrict__ cols, const float* __restrict__ vals,
    const float4* __restrict__ bias4,
    unsigned short* __restrict__ outHi, unsigned short* __restrict__ outLo) {
  const int wave = threadIdx.x >> 6;
  const int lane = threadIdx.x & 63;
  const int node = blockIdx.x * 4 + wave;

  const int lo = row_ptr[node];
  const int hi = row_ptr[node + 1];

  float4 acc = make_float4(0.f, 0.f, 0.f, 0.f);
  int e = lo;
  for (; e + 4 <= hi; e += 4) {
    const int c0 = cols[e + 0], c1 = cols[e + 1], c2 = cols[e + 2], c3 = cols[e + 3];
    const float w0 = vals[e + 0], w1 = vals[e + 1], w2 = vals[e + 2], w3 = vals[e + 3];
    const float4 r0 = S4[(size_t)c0 * 64 + lane];
    const float4 r1 = S4[(size_t)c1 * 64 + lane];
    const float4 r2 = S4[(size_t)c2 * 64 + lane];
    const float4 r3 = S4[(size_t)c3 * 64 + lane];
    acc.x = fmaf(w0, r0.x, acc.x); acc.y = fmaf(w0, r0.y, acc.y);
    acc.z = fmaf(w0, r0.z, acc.z); acc.w = fmaf(w0, r0.w, acc.w);
    acc.x = fmaf(w1, r1.x, acc.x); acc.y = fmaf(w1, r1.y, acc.y);
    acc.z = fmaf(w1, r1.z, acc.z); acc.w = fmaf(w1, r1.w, acc.w);
    acc.x = fmaf(w2, r2.x, acc.x); acc.y = fmaf(w2, r2.y, acc.y);
    acc.z = fmaf(w2, r2.z, acc.z); acc.w = fmaf(w2, r2.w, acc.w);
    acc.x = fmaf(w3, r3.x, acc.x); acc.y = fmaf(w3, r3.y, acc.y);
    acc.z = fmaf(w3, r3.z, acc.z); acc.w = fmaf(w3, r3.w, acc.w);
  }
  for (; e < hi; ++e) {
    const int c = cols[e];
    const float w = vals[e];
    const float4 r = S4[(size_t)c * 64 + lane];
    acc.x = fmaf(w, r.x, acc.x); acc.y = fmaf(w, r.y, acc.y);
    acc.z = fmaf(w, r.z, acc.z); acc.w = fmaf(w, r.w, acc.w);
  }

  const float4 b = bias4[lane];
  acc.x = fmaxf(acc.x + b.x, 0.f);
  acc.y = fmaxf(acc.y + b.y, 0.f);
  acc.z = fmaxf(acc.z + b.z, 0.f);
  acc.w = fmaxf(acc.w + b.w, 0.f);

  ushort4 hv, lv;
  hv.x = bf16_rn(acc.x); lv.x = bf16_rn(acc.x - bf16_to_f(hv.x));
  hv.y = bf16_rn(acc.y); lv.y = bf16_rn(acc.y - bf16_to_f(hv.y));
  hv.z = bf16_rn(acc.z); lv.z = bf16_rn(acc.z - bf16_to_f(hv.z));
  hv.w = bf16_rn(acc.w); lv.w = bf16_rn(acc.w - bf16_to_f(hv.w));
  const size_t o = (size_t)node * NHID + lane * 4;
  *(ushort4*)&outHi[o] = hv;
  *(ushort4*)&outLo[o] = lv;
}

// ---------------------------------------------------------------------------
// SpMM F=128: one wave per node; half-waves process alternating edges with
// float4 (full 1KB/wave/instr), 2-edge unroll per half, shfl_xor combine.
// ---------------------------------------------------------------------------
__global__ __launch_bounds__(256) void spmm128_f32(
    const float4* __restrict__ S4, const int* __restrict__ row_ptr,
    const int* __restrict__ cols, const float* __restrict__ vals,
    const float4* __restrict__ bias4, float4* __restrict__ out4) {
  const int wave = threadIdx.x >> 6;
  const int lane = threadIdx.x & 63;
  const int half = lane >> 5;
  const int l32  = lane & 31;
  const int node = blockIdx.x * 4 + wave;

  const int lo = row_ptr[node];
  const int hi = row_ptr[node + 1];

  float4 acc = make_float4(0.f, 0.f, 0.f, 0.f);
  int e = lo + half;
  for (; e + 2 < hi; e += 4) {
    const int c0 = cols[e], c1 = cols[e + 2];
    const float w0 = vals[e], w1 = vals[e + 2];
    const float4 r0 = S4[(size_t)c0 * 32 + l32];
    const float4 r1 = S4[(size_t)c1 * 32 + l32];
    acc.x = fmaf(w0, r0.x, acc.x); acc.y = fmaf(w0, r0.y, acc.y);
    acc.z = fmaf(w0, r0.z, acc.z); acc.w = fmaf(w0, r0.w, acc.w);
    acc.x = fmaf(w1, r1.x, acc.x); acc.y = fmaf(w1, r1.y, acc.y);
    acc.z = fmaf(w1, r1.z, acc.z); acc.w = fmaf(w1, r1.w, acc.w);
  }
  for (; e < hi; e += 2) {
    const int c = cols[e];
    const float w = vals[e];
    const float4 r = S4[(size_t)c * 32 + l32];
    acc.x = fmaf(w, r.x, acc.x); acc.y = fmaf(w, r.y, acc.y);
    acc.z = fmaf(w, r.z, acc.z); acc.w = fmaf(w, r.w, acc.w);
  }

  // combine the two half-wave partial sums
  acc.x += __shfl_xor(acc.x, 32);
  acc.y += __shfl_xor(acc.y, 32);
  acc.z += __shfl_xor(acc.z, 32);
  acc.w += __shfl_xor(acc.w, 32);

  if (half == 0) {
    const float4 b = bias4[l32];
    acc.x += b.x; acc.y += b.y; acc.z += b.z; acc.w += b.w;
    out4[(size_t)node * 32 + l32] = acc;
  }
}

// ---------------------------------------------------------------------------
// fp32 tiled GEMM (head only)
// ---------------------------------------------------------------------------
template <bool SIGMOID>
__global__ __launch_bounds__(256) void gemm_rrr(
    const float* __restrict__ A, const float* __restrict__ B,
    float* __restrict__ C, int M, int N, int K) {
  __shared__ float As[16][132];
  __shared__ float Bs[16][132];

  const int tid = threadIdx.x;
  const int tx = tid & 15;
  const int ty = tid >> 4;
  const int m0 = blockIdx.y * 128;
  const int n0 = blockIdx.x * 128;

  const int arow  = tid >> 2;
  const int acol4 = (tid & 3) * 4;
  const int brow  = tid >> 5;
  const int bcol4 = (tid & 31) * 4;

  float acc[8][8];
#pragma unroll
  for (int i = 0; i < 8; ++i)
#pragma unroll
    for (int j = 0; j < 8; ++j) acc[i][j] = 0.f;

  for (int k0 = 0; k0 < K; k0 += 16) {
#pragma unroll
    for (int p = 0; p < 2; ++p) {
      const int mt = p * 64 + arow;
      const int m  = m0 + mt;
      float4 av = make_float4(0.f, 0.f, 0.f, 0.f);
      if (m < M) av = *(const float4*)&A[(size_t)m * K + k0 + acol4];
      As[acol4 + 0][mt] = av.x;
      As[acol4 + 1][mt] = av.y;
      As[acol4 + 2][mt] = av.z;
      As[acol4 + 3][mt] = av.w;
    }
#pragma unroll
    for (int p = 0; p < 2; ++p) {
      const int kt = p * 8 + brow;
      *(float4*)&Bs[kt][bcol4] = *(const float4*)&B[(size_t)(k0 + kt) * N + n0 + bcol4];
    }
    __syncthreads();
#pragma unroll
    for (int k = 0; k < 16; ++k) {
      float a[8], b[8];
      *(float4*)&a[0] = *(const float4*)&As[k][ty * 4];
      *(float4*)&a[4] = *(const float4*)&As[k][64 + ty * 4];
      *(float4*)&b[0] = *(const float4*)&Bs[k][tx * 4];
      *(float4*)&b[4] = *(const float4*)&Bs[k][64 + tx * 4];
#pragma unroll
      for (int i = 0; i < 8; ++i)
#pragma unroll
        for (int j = 0; j < 8; ++j)
          acc[i][j] = fmaf(a[i], b[j], acc[i][j]);
    }
    __syncthreads();
  }

#pragma unroll
  for (int ih = 0; ih < 2; ++ih)
#pragma unroll
    for (int i = 0; i < 4; ++i) {
      const int m = m0 + ih * 64 + ty * 4 + i;
      if (m < M) {
#pragma unroll
        for (int jh = 0; jh < 2; ++jh) {
          float4 v = *(float4*)&acc[ih * 4 + i][jh * 4];
          if (SIGMOID) {
            v.x = 1.f / (1.f + expf(-v.x));
            v.y = 1.f / (1.f + expf(-v.y));
            v.z = 1.f / (1.f + expf(-v.z));
            v.w = 1.f / (1.f + expf(-v.w));
          }
          *(float4*)&C[(size_t)m * N + n0 + jh * 64 + tx * 4] = v;
        }
      }
    }
}

// ---------------------------------------------------------------------------
// Head helpers
// ---------------------------------------------------------------------------
__global__ __launch_bounds__(128) void transpose_we(
    const float* __restrict__ We, float* __restrict__ WeT) {
  WeT[blockIdx.x * NCLASS + threadIdx.x] = We[threadIdx.x * NCLASS + blockIdx.x];
}

__global__ __launch_bounds__(128) void gather_rows(
    const float* __restrict__ Z, const int* __restrict__ idx,
    float* __restrict__ out) {
  out[blockIdx.x * NCLASS + threadIdx.x] =
      Z[(size_t)idx[blockIdx.x] * NCLASS + threadIdx.x];
}

__global__ __launch_bounds__(256) void gather_rows_t(
    const float* __restrict__ Z, const int* __restrict__ idx,
    float* __restrict__ out) {
  const int g = blockIdx.x * 256 + threadIdx.x;
  const int j = g & (N_UV - 1);
  const int k = g >> 11;
  out[(size_t)k * N_UV + j] = Z[(size_t)idx[j] * NCLASS + k];
}

// ---------------------------------------------------------------------------
// Launch
// ---------------------------------------------------------------------------
extern "C" void kernel_launch(void* const* d_in, const int* in_sizes, int n_in,
                              void* d_out, int out_size, void* d_ws, size_t ws_size,
                              hipStream_t stream) {
  const int*   u       = (const int*)  d_in[0];
  const int*   v       = (const int*)  d_in[1];
  const float* x       = (const float*)d_in[2];
  const int*   adj_row = (const int*)  d_in[3];
  const int*   adj_col = (const int*)  d_in[4];
  const float* adj_val = (const float*)d_in[5];
  const float* W1      = (const float*)d_in[6];
  const float* b1      = (const float*)d_in[7];
  const float* W2      = (const float*)d_in[8];
  const float* b2      = (const float*)d_in[9];
  const float* We      = (const float*)d_in[10];
  float* out = (float*)d_out;

  char* wsb = (char*)d_ws;
  // Region A [0, 51.2MB): S1; after spmm1 dead -> S2 [0,25.6) + Z [25.6,51.2)
  float* S1 = (float*)wsb;
  float* S2 = (float*)wsb;
  float* Z  = (float*)(wsb + (size_t)N_NODES * NCLASS * sizeof(float));
  // Region B [51.2MB, 102.4MB): Hhi/Hlo; after GEMM2 dead -> head scratch
  char* rB = wsb + (size_t)N_NODES * NHID * sizeof(float);
  unsigned short* Hhi = (unsigned short*)rB;
  unsigned short* Hlo = Hhi + (size_t)N_NODES * NHID;
  float* WeT = (float*)rB;
  float* ZUG = WeT + NCLASS * NCLASS;
  float* ZVT = ZUG + N_UV * NCLASS;
  float* ZU  = ZVT + N_UV * NCLASS;
  // Split weights + row_ptr parked in d_out (dead until the final GEMM)
  unsigned short* W1Thi = (unsigned short*)out;
  unsigned short* W1Tlo = W1Thi + NHID * NFEAT;
  unsigned short* W2Thi = W1Tlo + NHID * NFEAT;
  unsigned short* W2Tlo = W2Thi + NCLASS * NHID;
  int* row_ptr = (int*)(W2Tlo + NCLASS * NHID);   // 50001 ints

  // 0) weight prep + row_ptr build
  split_transpose<<<(NFEAT * NHID + 255) / 256, 256, 0, stream>>>(W1, W1Thi, W1Tlo, NFEAT, NHID);
  split_transpose<<<(NHID * NCLASS + 255) / 256, 256, 0, stream>>>(W2, W2Thi, W2Tlo, NHID, NCLASS);
  build_row_ptr<<<(N_EDGES + 255) / 256, 256, 0, stream>>>(adj_row, row_ptr);

  // 1) S1 = x @ W1  (MFMA split-bf16)
  gemm_mfma_split<true><<<dim3(NHID / 128, (N_NODES + 127) / 128), 256, 0, stream>>>(
      x, nullptr, nullptr, W1Thi, W1Tlo, S1, N_NODES, NHID, NFEAT);

  // 2) Hhi/Hlo = split(relu(A @ S1 + b1))
  spmm256_split<<<N_NODES / 4, 256, 0, stream>>>(
      (const float4*)S1, row_ptr, adj_col, adj_val, (const float4*)b1, Hhi, Hlo);

  // 3) S2 = H @ W2  (MFMA split-bf16)
  gemm_mfma_split<false><<<dim3(NCLASS / 128, (N_NODES + 127) / 128), 256, 0, stream>>>(
      nullptr, Hhi, Hlo, W2Thi, W2Tlo, S2, N_NODES, NCLASS, NHID);

  // 4) Z = A @ S2 + b2
  spmm128_f32<<<N_NODES / 4, 256, 0, stream>>>(
      (const float4*)S2, row_ptr, adj_col, adj_val, (const float4*)b2, (float4*)Z);

  // 5) head
  transpose_we<<<NCLASS, NCLASS, 0, stream>>>(We, WeT);
  gather_rows<<<N_UV, NCLASS, 0, stream>>>(Z, u, ZUG);
  gather_rows_t<<<(N_UV * NCLASS) / 256, 256, 0, stream>>>(Z, v, ZVT);

  // 6) ZU = ZUG @ WeT
  gemm_rrr<false><<<dim3(NCLASS / 128, N_UV / 128), 256, 0, stream>>>(
      ZUG, WeT, ZU, N_UV, NCLASS, NCLASS);

  // 7) out = sigmoid(ZU @ ZVT)
  gemm_rrr<true><<<dim3(N_UV / 128, N_UV / 128), 256, 0, stream>>>(
      ZU, ZVT, out, N_UV, N_UV, NCLASS);
}